// Round 3
// baseline (281.926 us; speedup 1.0000x reference)
//
#include <hip/hip_runtime.h>
#include <hip/hip_cooperative_groups.h>

namespace cg = cooperative_groups;

// GAT layer, N=8192, IN_F=512, OUT_F=64, alpha=0.2
// exp(lrelu(s1_i+s2_j)) factors on each side of s2_j <= -s1_i =>
// softmax row = [A_i*suffix(exp(s2)*Wh) + B_i*prefix(exp(.2 s2)*Wh)] / (scalar same)
// over s2 sorted ascending. O(N*F). Single cooperative kernel, 5 phases.

constexpr int NV   = 8192;
constexpr int FIN  = 512;
constexpr int FOUT = 64;
constexpr int NB   = 512;   // blocks
constexpr int NT   = 512;   // threads/block (8 waves)
constexpr int CH   = 32;    // sorted positions per chunk
constexpr int NCH  = 256;   // NV / CH
constexpr int RPB  = NV / NB;  // 16 rows (and ids) per block

__device__ __forceinline__ unsigned f2key(float x) {
    unsigned b = __float_as_uint(x);
    return (b & 0x80000000u) ? ~b : (b | 0x80000000u);  // order-preserving
}

__global__ __launch_bounds__(NT, 4) void gat_fused(
    const float* __restrict__ h, const float* __restrict__ W,
    const float* __restrict__ a, float* __restrict__ out,
    float* __restrict__ Wh, float* __restrict__ s1, float* __restrict__ s2g,
    int* __restrict__ sortedIdx, unsigned* __restrict__ sortedKey,
    float* __restrict__ sortedU, float* __restrict__ sortedV,
    float* __restrict__ chunkU, float* __restrict__ chunkV,
    float* __restrict__ suc, float* __restrict__ svc,
    float* __restrict__ Usuf, float* __restrict__ Vpref,
    float* __restrict__ susuf, float* __restrict__ svpref,
    int coopMode, int phaseLo, int phaseHi)
{
    __shared__ float smem[8192];     // 32 KB: W-chunk (P1) / keys (P2)
    __shared__ float extras[1040];   // P3 partials / P4 segment totals
    const int t    = threadIdx.x;
    const int b    = blockIdx.x;
    const int lane = t & 63;
    const int w    = t >> 6;

    // ================= P1: Wh = h @ W^T ; s1 ; s2 =================
    if (phaseLo <= 0 && 0 <= phaseHi) {
        const int row0 = __builtin_amdgcn_readfirstlane(b * RPB + w * 2);
        float4 A0 = {0.f,0.f,0.f,0.f}, A1 = {0.f,0.f,0.f,0.f};
        const float4* Wf4 = reinterpret_cast<const float4*>(W);
        float4* S4 = reinterpret_cast<float4*>(smem);
        for (int pass = 0; pass < 4; ++pass) {
            // stage W[:, pass*128 .. +128) into LDS, rotation-swizzled:
            // granule (kk4,f) -> S4[kk4*64 + ((f+kk4)&63)]
            #pragma unroll
            for (int it = 0; it < 4; ++it) {
                const int g = it * 512 + t;          // 0..2047
                const int f = g >> 5, kk4 = g & 31;
                S4[kk4 * 64 + ((f + kk4) & 63)] = Wf4[f * 128 + pass * 32 + kk4];
            }
            __syncthreads();
            const float* hb = h + (size_t)row0 * FIN + pass * 128;
            #pragma unroll 8
            for (int k4 = 0; k4 < 32; ++k4) {
                const float4 wv = S4[k4 * 64 + ((lane + k4) & 63)];
                const float4 h0 = *reinterpret_cast<const float4*>(hb + k4 * 4);
                const float4 h1 = *reinterpret_cast<const float4*>(hb + FIN + k4 * 4);
                A0.x = fmaf(h0.x, wv.x, A0.x); A0.y = fmaf(h0.y, wv.y, A0.y);
                A0.z = fmaf(h0.z, wv.z, A0.z); A0.w = fmaf(h0.w, wv.w, A0.w);
                A1.x = fmaf(h1.x, wv.x, A1.x); A1.y = fmaf(h1.y, wv.y, A1.y);
                A1.z = fmaf(h1.z, wv.z, A1.z); A1.w = fmaf(h1.w, wv.w, A1.w);
            }
            __syncthreads();
        }
        const float acc0 = (A0.x + A0.y) + (A0.z + A0.w);
        const float acc1 = (A1.x + A1.y) + (A1.z + A1.w);
        Wh[(size_t)row0 * FOUT + lane] = acc0;
        Wh[(size_t)(row0 + 1) * FOUT + lane] = acc1;
        const float a1 = a[lane], a2 = a[FOUT + lane];
        float r0s1 = acc0 * a1, r0s2 = acc0 * a2;
        float r1s1 = acc1 * a1, r1s2 = acc1 * a2;
        #pragma unroll
        for (int off = 32; off > 0; off >>= 1) {
            r0s1 += __shfl_xor(r0s1, off);
            r0s2 += __shfl_xor(r0s2, off);
            r1s1 += __shfl_xor(r1s1, off);
            r1s2 += __shfl_xor(r1s2, off);
        }
        if (lane == 0) {
            s1[row0] = r0s1;     s2g[row0] = r0s2;
            s1[row0 + 1] = r1s1; s2g[row0 + 1] = r1s2;
        }
    }
    if (coopMode) cg::this_grid().sync();

    // ================= P2: rank by unique key, scatter sorted arrays =======
    if (phaseLo <= 1 && 1 <= phaseHi) {
        unsigned* ks = reinterpret_cast<unsigned*>(smem);
        #pragma unroll
        for (int q = 0; q < NV / NT; ++q) {
            const int j = q * NT + t;
            ks[j] = (f2key(s2g[j]) & 0xFFFFE000u) | (unsigned)j;  // unique keys
        }
        __syncthreads();
        const int seg = t & 31;            // 32 threads cooperate per id
        const int id  = b * RPB + (t >> 5);
        const unsigned key = ks[id];
        int cnt = 0;
        const uint4* K4 = reinterpret_cast<const uint4*>(ks);
        #pragma unroll 4
        for (int kk = 0; kk < 64; ++kk) {
            const uint4 v = K4[kk * 32 + seg];   // contiguous across lanes
            cnt += (int)(v.x < key) + (int)(v.y < key)
                 + (int)(v.z < key) + (int)(v.w < key);
        }
        cnt += __shfl_xor(cnt, 1);
        cnt += __shfl_xor(cnt, 2);
        cnt += __shfl_xor(cnt, 4);
        cnt += __shfl_xor(cnt, 8);
        cnt += __shfl_xor(cnt, 16);
        if (seg == 0) {
            sortedKey[cnt] = key;
            sortedIdx[cnt] = id;
            const float x = s2g[id];
            sortedU[cnt] = __expf(x);
            sortedV[cnt] = __expf(0.2f * x);
        }
    }
    if (coopMode) cg::this_grid().sync();

    // ================= P3: per-chunk sums (blocks 0..255) ==================
    if (phaseLo <= 2 && 2 <= phaseHi && b < NCH) {
        const int c = b;
        float au = 0.f, av = 0.f, su = 0.f, sv = 0.f;
        #pragma unroll
        for (int q = 0; q < 4; ++q) {
            const int p = c * CH + w * 4 + q;
            const int j = sortedIdx[p];
            const float u = sortedU[p];
            const float v = sortedV[p];
            const float wh = Wh[(size_t)j * FOUT + lane];
            au = fmaf(u, wh, au); av = fmaf(v, wh, av);
            su += u; sv += v;
        }
        float* pU  = extras;          // [8][64]
        float* pV  = extras + 512;    // [8][64]
        float* psU = extras + 1024;   // [8]
        float* psV = extras + 1032;   // [8]
        pU[w * 64 + lane] = au;
        pV[w * 64 + lane] = av;
        if (lane == 0) { psU[w] = su; psV[w] = sv; }
        __syncthreads();
        if (t < 64) {
            float s = 0.f;
            #pragma unroll
            for (int q = 0; q < 8; ++q) s += pU[q * 64 + t];
            chunkU[c * FOUT + t] = s;
        } else if (t < 128) {
            const int f = t - 64;
            float s = 0.f;
            #pragma unroll
            for (int q = 0; q < 8; ++q) s += pV[q * 64 + f];
            chunkV[c * FOUT + f] = s;
        } else if (t == 128) {
            float s = 0.f;
            #pragma unroll
            for (int q = 0; q < 8; ++q) s += psU[q];
            suc[c] = s;
        } else if (t == 129) {
            float s = 0.f;
            #pragma unroll
            for (int q = 0; q < 8; ++q) s += psV[q];
            svc[c] = s;
        }
    }
    if (coopMode) cg::this_grid().sync();

    // ================= P4: scans (block 0 = U suffix, block 1 = V prefix) ==
    if (phaseLo <= 3 && 3 <= phaseHi) {
        if (b == 0) {
            const int f = lane, seg = w;       // 8 segments x 32 chunks
            float run = 0.f;
            for (int q0 = 31; q0 >= 0; q0 -= 8) {
                float tmp[8];
                #pragma unroll
                for (int e = 0; e < 8; ++e) tmp[e] = chunkU[(seg * 32 + q0 - e) * FOUT + f];
                #pragma unroll
                for (int e = 0; e < 8; ++e) { run += tmp[e]; Usuf[(seg * 32 + q0 - e) * FOUT + f] = run; }
            }
            extras[seg * 64 + f] = run;
            if (t < 8) {
                float r = 0.f;
                for (int cq = t * 32 + 31; cq >= t * 32; --cq) { r += suc[cq]; susuf[cq] = r; }
                extras[512 + t] = r;
            }
            __syncthreads();
            float off = 0.f;
            #pragma unroll
            for (int s = 0; s < 8; ++s) if (s > seg) off += extras[s * 64 + f];
            for (int q0 = 0; q0 < 32; q0 += 8) {
                #pragma unroll
                for (int e = 0; e < 8; ++e) Usuf[(seg * 32 + q0 + e) * FOUT + f] += off;
            }
            if (t < 64) { Usuf[256 * FOUT + t] = 0.f; Usuf[257 * FOUT + t] = 0.f; }
            if (t < 8) {
                float o = 0.f;
                for (int s = t + 1; s < 8; ++s) o += extras[512 + s];
                for (int cq = t * 32; cq < t * 32 + 32; ++cq) susuf[cq] += o;
            }
            if (t == 0) { susuf[256] = 0.f; susuf[257] = 0.f; }
        } else if (b == 1) {
            const int f = lane, seg = w;
            float run = 0.f;
            for (int q0 = 0; q0 < 32; q0 += 8) {
                float tmp[8];
                #pragma unroll
                for (int e = 0; e < 8; ++e) tmp[e] = chunkV[(seg * 32 + q0 + e) * FOUT + f];
                #pragma unroll
                for (int e = 0; e < 8; ++e) { Vpref[(seg * 32 + q0 + e) * FOUT + f] = run; run += tmp[e]; }
            }
            extras[seg * 64 + f] = run;
            if (t < 8) {
                float r = 0.f;
                for (int cq = t * 32; cq < t * 32 + 32; ++cq) { svpref[cq] = r; r += svc[cq]; }
                extras[512 + t] = r;
            }
            __syncthreads();
            float off = 0.f;
            #pragma unroll
            for (int s = 0; s < 8; ++s) if (s < seg) off += extras[s * 64 + f];
            for (int q0 = 0; q0 < 32; q0 += 8) {
                #pragma unroll
                for (int e = 0; e < 8; ++e) Vpref[(seg * 32 + q0 + e) * FOUT + f] += off;
            }
            if (seg == 0) {
                float tot = 0.f;
                #pragma unroll
                for (int s = 0; s < 8; ++s) tot += extras[s * 64 + f];
                Vpref[256 * FOUT + f] = tot;
            }
            if (t < 8) {
                float o = 0.f;
                for (int s = 0; s < t; ++s) o += extras[512 + s];
                for (int cq = t * 32; cq < t * 32 + 32; ++cq) svpref[cq] += o;
            }
            if (t == 0) {
                float tt = 0.f;
                for (int s = 0; s < 8; ++s) tt += extras[512 + s];
                svpref[256] = tt;
            }
        }
    }
    if (coopMode) cg::this_grid().sync();

    // ================= P5: per-row combine ================================
    if (phaseLo <= 4 && 4 <= phaseHi) {
        const int i0 = b * RPB + w * 2;
        #pragma unroll
        for (int r = 0; r < 2; ++r) {
            const int i = i0 + r;
            const float s1v = s1[i];
            const unsigned thr = (f2key(-s1v) & 0xFFFFE000u) | 0x1FFFu;
            // 3-round lane-parallel partition search: k = #{p: key[p] <= thr}
            const int pr1 = (sortedKey[lane * 128 + 127] <= thr) ? 1 : 0;
            const int B1 = __popcll(__ballot(pr1));
            int k;
            if (B1 >= 64) {
                k = NV;
            } else {
                const int base = B1 * 128;
                const int pr2 = (sortedKey[base + lane * 2 + 1] <= thr) ? 1 : 0;
                const int c2 = __popcll(__ballot(pr2));   // 0..63
                const int p3i = base + c2 * 2;
                k = p3i + ((sortedKey[p3i] <= thr) ? 1 : 0);
            }
            const int c = k >> 5;                 // 0..256
            float accU = 0.f, accV = 0.f, sau = 0.f, sav = 0.f;
            const int pst = c * CH;
            #pragma unroll 8
            for (int q = 0; q < CH; ++q) {
                const int p = pst + q;
                if (p < NV) {
                    const int j = sortedIdx[p];
                    const float wh = Wh[(size_t)j * FOUT + lane];
                    if (p < k) { const float v = sortedV[p]; accV = fmaf(v, wh, accV); sav += v; }
                    else       { const float u = sortedU[p]; accU = fmaf(u, wh, accU); sau += u; }
                }
            }
            const int cn = c + 1;
            const float A  = __expf(s1v);
            const float Bv = __expf(0.2f * s1v);
            const float numer = A * (Usuf[cn * FOUT + lane] + accU) + Bv * (Vpref[c * FOUT + lane] + accV);
            const float den   = A * (susuf[cn] + sau)               + Bv * (svpref[c] + sav);
            out[(size_t)i * FOUT + lane] = numer / den;
        }
    }
}

// ----------------------------------------------------------------
extern "C" void kernel_launch(void* const* d_in, const int* in_sizes, int n_in,
                              void* d_out, int out_size, void* d_ws, size_t ws_size,
                              hipStream_t stream) {
    (void)in_sizes; (void)n_in; (void)out_size; (void)ws_size;
    const float* h = (const float*)d_in[0];
    // d_in[1] = adj : unused by the reference computation
    const float* W = (const float*)d_in[2];
    const float* a = (const float*)d_in[3];
    float* out = (float*)d_out;

    int*      sortedIdx = (int*)d_ws;
    unsigned* sortedKey = (unsigned*)d_ws + NV;
    float* fws = (float*)d_ws + 2 * NV;
    float* Wh      = fws;  fws += (size_t)NV * FOUT;
    float* s1      = fws;  fws += NV;
    float* s2g     = fws;  fws += NV;
    float* sortedU = fws;  fws += NV;
    float* sortedV = fws;  fws += NV;
    float* chunkU  = fws;  fws += NCH * FOUT;
    float* chunkV  = fws;  fws += NCH * FOUT;
    float* suc     = fws;  fws += NCH;
    float* svc     = fws;  fws += NCH;
    float* Usuf    = fws;  fws += 258 * FOUT;
    float* Vpref   = fws;  fws += 257 * FOUT;
    float* susuf   = fws;  fws += 258;
    float* svpref  = fws;  fws += 257;

    int coopMode = 1, lo = 0, hi = 4;
    void* args[] = {
        (void*)&h, (void*)&W, (void*)&a, (void*)&out,
        (void*)&Wh, (void*)&s1, (void*)&s2g,
        (void*)&sortedIdx, (void*)&sortedKey, (void*)&sortedU, (void*)&sortedV,
        (void*)&chunkU, (void*)&chunkV, (void*)&suc, (void*)&svc,
        (void*)&Usuf, (void*)&Vpref, (void*)&susuf, (void*)&svpref,
        (void*)&coopMode, (void*)&lo, (void*)&hi
    };
    hipError_t err = hipLaunchCooperativeKernel(
        (const void*)gat_fused, dim3(NB), dim3(NT), args, 0, stream);

    if (err != hipSuccess) {
        // fallback: one launch per phase, grid.sync never executed
        for (int p = 0; p < 5; ++p) {
            hipLaunchKernelGGL(gat_fused, dim3(NB), dim3(NT), 0, stream,
                               h, W, a, out, Wh, s1, s2g,
                               sortedIdx, sortedKey, sortedU, sortedV,
                               chunkU, chunkV, suc, svc,
                               Usuf, Vpref, susuf, svpref,
                               0, p, p);
        }
    }
}

// Round 4
// 199.823 us; speedup vs baseline: 1.4109x; 1.4109x over previous
//
#include <hip/hip_runtime.h>
#include <hip/hip_cooperative_groups.h>

// GAT layer, N=8192, IN_F=512, OUT_F=64, alpha=0.2
// exp(lrelu(s1_i+s2_j)) factors on each side of s2_j <= -s1_i =>
// softmax row = [A_i*suffix(exp(s2)*Wh) + B_i*prefix(exp(.2 s2)*Wh)] / (scalar same)
// over s2 sorted ascending. O(N*F). Single coop kernel, custom grid barriers
// (cg::grid.sync measured ~60us each on MI355X -> replaced with
//  release-add / relaxed-spin / acquire-load device-scope barrier).

constexpr int NV   = 8192;
constexpr int FIN  = 512;
constexpr int FOUT = 64;
constexpr int NB   = 512;   // blocks
constexpr int NT   = 512;   // threads/block (8 waves)
constexpr int CH   = 16;    // sorted positions per chunk
constexpr int NCH  = 512;   // NV / CH
constexpr int RPB  = NV / NB;  // 16 rows (and ids) per block

__device__ __forceinline__ unsigned f2key(float x) {
    unsigned b = __float_as_uint(x);
    return (b & 0x80000000u) ? ~b : (b | 0x80000000u);  // order-preserving
}

// Device-scope grid barrier. One release-RMW per block (flushes this XCD's L2
// once), relaxed spin (no repeated invalidation), one acquire load at the end
// (invalidates this CU's L1 + XCD L2 so post-barrier reads see remote writes).
__device__ __forceinline__ void gbar(unsigned* c, unsigned target) {
    __syncthreads();   // drains vmcnt: all block stores are in L2 before RMW
    if (threadIdx.x == 0) {
        __hip_atomic_fetch_add(c, 1u, __ATOMIC_RELEASE, __HIP_MEMORY_SCOPE_AGENT);
        while (__hip_atomic_load(c, __ATOMIC_RELAXED, __HIP_MEMORY_SCOPE_AGENT) < target)
            __builtin_amdgcn_s_sleep(2);
        (void)__hip_atomic_load(c, __ATOMIC_ACQUIRE, __HIP_MEMORY_SCOPE_AGENT);
    }
    __syncthreads();
}

__global__ __launch_bounds__(NT, 4) void gat_fused(
    const float* __restrict__ h, const float* __restrict__ W,
    const float* __restrict__ a, float* __restrict__ out,
    float* __restrict__ Wh, float* __restrict__ s1, float* __restrict__ s2g,
    int* __restrict__ sortedIdx, unsigned* __restrict__ sortedKey,
    float* __restrict__ sortedU, float* __restrict__ sortedV,
    float* __restrict__ chunkU, float* __restrict__ chunkV,
    float* __restrict__ suc, float* __restrict__ svc,
    float* __restrict__ Usuf, float* __restrict__ Vpref,
    float* __restrict__ susuf, float* __restrict__ svpref,
    unsigned* __restrict__ bar,
    int coopMode, int phaseLo, int phaseHi)
{
    __shared__ float smem[8192];     // 32 KB: W-chunk (P1) / keys (P2)
    __shared__ float extras[1040];   // P3 partials / P4 segment totals
    const int t    = threadIdx.x;
    const int b    = blockIdx.x;
    const int lane = t & 63;
    const int w    = t >> 6;

    // ================= P1: Wh = h @ W^T ; s1 ; s2 =================
    if (phaseLo <= 0 && 0 <= phaseHi) {
        const int row0 = __builtin_amdgcn_readfirstlane(b * RPB + w * 2);
        float4 A0 = {0.f,0.f,0.f,0.f}, A1 = {0.f,0.f,0.f,0.f};
        const float4* Wf4 = reinterpret_cast<const float4*>(W);
        float4* S4 = reinterpret_cast<float4*>(smem);
        for (int pass = 0; pass < 4; ++pass) {
            // stage W[:, pass*128 .. +128) into LDS, rotation-swizzled
            #pragma unroll
            for (int it = 0; it < 4; ++it) {
                const int g = it * 512 + t;          // 0..2047
                const int f = g >> 5, kk4 = g & 31;
                S4[kk4 * 64 + ((f + kk4) & 63)] = Wf4[f * 128 + pass * 32 + kk4];
            }
            __syncthreads();
            const float* hb = h + (size_t)row0 * FIN + pass * 128;
            #pragma unroll 8
            for (int k4 = 0; k4 < 32; ++k4) {
                const float4 wv = S4[k4 * 64 + ((lane + k4) & 63)];
                const float4 h0 = *reinterpret_cast<const float4*>(hb + k4 * 4);
                const float4 h1 = *reinterpret_cast<const float4*>(hb + FIN + k4 * 4);
                A0.x = fmaf(h0.x, wv.x, A0.x); A0.y = fmaf(h0.y, wv.y, A0.y);
                A0.z = fmaf(h0.z, wv.z, A0.z); A0.w = fmaf(h0.w, wv.w, A0.w);
                A1.x = fmaf(h1.x, wv.x, A1.x); A1.y = fmaf(h1.y, wv.y, A1.y);
                A1.z = fmaf(h1.z, wv.z, A1.z); A1.w = fmaf(h1.w, wv.w, A1.w);
            }
            __syncthreads();
        }
        const float acc0 = (A0.x + A0.y) + (A0.z + A0.w);
        const float acc1 = (A1.x + A1.y) + (A1.z + A1.w);
        Wh[(size_t)row0 * FOUT + lane] = acc0;
        Wh[(size_t)(row0 + 1) * FOUT + lane] = acc1;
        const float a1 = a[lane], a2 = a[FOUT + lane];
        float r0s1 = acc0 * a1, r0s2 = acc0 * a2;
        float r1s1 = acc1 * a1, r1s2 = acc1 * a2;
        #pragma unroll
        for (int off = 32; off > 0; off >>= 1) {
            r0s1 += __shfl_xor(r0s1, off);
            r0s2 += __shfl_xor(r0s2, off);
            r1s1 += __shfl_xor(r1s1, off);
            r1s2 += __shfl_xor(r1s2, off);
        }
        if (lane == 0) {
            s1[row0] = r0s1;     s2g[row0] = r0s2;
            s1[row0 + 1] = r1s1; s2g[row0 + 1] = r1s2;
        }
    }
    if (coopMode) gbar(bar + 0, NB);

    // ================= P2: rank by unique key, scatter sorted arrays =======
    if (phaseLo <= 1 && 1 <= phaseHi) {
        unsigned* ks = reinterpret_cast<unsigned*>(smem);
        #pragma unroll
        for (int q = 0; q < NV / NT; ++q) {
            const int j = q * NT + t;
            ks[j] = (f2key(s2g[j]) & 0xFFFFE000u) | (unsigned)j;  // unique keys
        }
        __syncthreads();
        const int seg = t & 31;            // 32 threads cooperate per id
        const int id  = b * RPB + (t >> 5);
        const unsigned key = ks[id];
        int cnt = 0;
        const uint4* K4 = reinterpret_cast<const uint4*>(ks);
        #pragma unroll 4
        for (int kk = 0; kk < 64; ++kk) {
            const uint4 v = K4[kk * 32 + seg];   // contiguous across lanes
            cnt += (int)(v.x < key) + (int)(v.y < key)
                 + (int)(v.z < key) + (int)(v.w < key);
        }
        cnt += __shfl_xor(cnt, 1);
        cnt += __shfl_xor(cnt, 2);
        cnt += __shfl_xor(cnt, 4);
        cnt += __shfl_xor(cnt, 8);
        cnt += __shfl_xor(cnt, 16);
        if (seg == 0) {
            sortedKey[cnt] = key;
            sortedIdx[cnt] = id;
            const float x = s2g[id];
            sortedU[cnt] = __expf(x);
            sortedV[cnt] = __expf(0.2f * x);
        }
    }
    if (coopMode) gbar(bar + 1, NB);

    // ================= P3: per-chunk sums (all 512 blocks, chunk = b) ======
    if (phaseLo <= 2 && 2 <= phaseHi) {
        const int c = b;
        float au = 0.f, av = 0.f, su = 0.f, sv = 0.f;
        #pragma unroll
        for (int q = 0; q < 2; ++q) {
            const int p = c * CH + w * 2 + q;
            const int j = sortedIdx[p];
            const float u = sortedU[p];
            const float v = sortedV[p];
            const float wh = Wh[(size_t)j * FOUT + lane];
            au = fmaf(u, wh, au); av = fmaf(v, wh, av);
            su += u; sv += v;
        }
        float* pU  = extras;          // [8][64]
        float* pV  = extras + 512;    // [8][64]
        float* psU = extras + 1024;   // [8]
        float* psV = extras + 1032;   // [8]
        pU[w * 64 + lane] = au;
        pV[w * 64 + lane] = av;
        if (lane == 0) { psU[w] = su; psV[w] = sv; }
        __syncthreads();
        if (t < 64) {
            float s = 0.f;
            #pragma unroll
            for (int q = 0; q < 8; ++q) s += pU[q * 64 + t];
            chunkU[c * FOUT + t] = s;
        } else if (t < 128) {
            const int f = t - 64;
            float s = 0.f;
            #pragma unroll
            for (int q = 0; q < 8; ++q) s += pV[q * 64 + f];
            chunkV[c * FOUT + f] = s;
        } else if (t == 128) {
            float s = 0.f;
            #pragma unroll
            for (int q = 0; q < 8; ++q) s += psU[q];
            suc[c] = s;
        } else if (t == 129) {
            float s = 0.f;
            #pragma unroll
            for (int q = 0; q < 8; ++q) s += psV[q];
            svc[c] = s;
        }
    }
    if (coopMode) gbar(bar + 2, NB);

    // ================= P4: scans (block 0 = U suffix, block 1 = V prefix) ==
    if (phaseLo <= 3 && 3 <= phaseHi) {
        if (b == 0) {
            const int f = lane, seg = w;       // 8 segments x 64 chunks
            float run = 0.f;
            for (int q0 = 63; q0 >= 0; q0 -= 8) {
                float tmp[8];
                #pragma unroll
                for (int e = 0; e < 8; ++e) tmp[e] = chunkU[(seg * 64 + q0 - e) * FOUT + f];
                #pragma unroll
                for (int e = 0; e < 8; ++e) { run += tmp[e]; Usuf[(seg * 64 + q0 - e) * FOUT + f] = run; }
            }
            extras[seg * 64 + f] = run;
            if (t < 8) {
                float r = 0.f;
                for (int cq = t * 64 + 63; cq >= t * 64; --cq) { r += suc[cq]; susuf[cq] = r; }
                extras[512 + t] = r;
            }
            __syncthreads();
            float off = 0.f;
            #pragma unroll
            for (int s = 0; s < 8; ++s) if (s > seg) off += extras[s * 64 + f];
            for (int q0 = 0; q0 < 64; q0 += 8) {
                #pragma unroll
                for (int e = 0; e < 8; ++e) Usuf[(seg * 64 + q0 + e) * FOUT + f] += off;
            }
            if (t < 64) { Usuf[512 * FOUT + t] = 0.f; Usuf[513 * FOUT + t] = 0.f; }
            if (t < 8) {
                float o = 0.f;
                for (int s = t + 1; s < 8; ++s) o += extras[512 + s];
                for (int cq = t * 64; cq < t * 64 + 64; ++cq) susuf[cq] += o;
            }
            if (t == 0) { susuf[512] = 0.f; susuf[513] = 0.f; }
        } else if (b == 1) {
            const int f = lane, seg = w;
            float run = 0.f;
            for (int q0 = 0; q0 < 64; q0 += 8) {
                float tmp[8];
                #pragma unroll
                for (int e = 0; e < 8; ++e) tmp[e] = chunkV[(seg * 64 + q0 + e) * FOUT + f];
                #pragma unroll
                for (int e = 0; e < 8; ++e) { Vpref[(seg * 64 + q0 + e) * FOUT + f] = run; run += tmp[e]; }
            }
            extras[seg * 64 + f] = run;
            if (t < 8) {
                float r = 0.f;
                for (int cq = t * 64; cq < t * 64 + 64; ++cq) { svpref[cq] = r; r += svc[cq]; }
                extras[512 + t] = r;
            }
            __syncthreads();
            float off = 0.f;
            #pragma unroll
            for (int s = 0; s < 8; ++s) if (s < seg) off += extras[s * 64 + f];
            for (int q0 = 0; q0 < 64; q0 += 8) {
                #pragma unroll
                for (int e = 0; e < 8; ++e) Vpref[(seg * 64 + q0 + e) * FOUT + f] += off;
            }
            if (seg == 0) {
                float tot = 0.f;
                #pragma unroll
                for (int s = 0; s < 8; ++s) tot += extras[s * 64 + f];
                Vpref[512 * FOUT + f] = tot;
            }
            if (t < 8) {
                float o = 0.f;
                for (int s = 0; s < t; ++s) o += extras[512 + s];
                for (int cq = t * 64; cq < t * 64 + 64; ++cq) svpref[cq] += o;
            }
            if (t == 0) {
                float tt = 0.f;
                for (int s = 0; s < 8; ++s) tt += extras[512 + s];
                svpref[512] = tt;
            }
        }
    }
    if (coopMode) gbar(bar + 3, NB);

    // ================= P5: per-row combine ================================
    if (phaseLo <= 4 && 4 <= phaseHi) {
        const int i0 = b * RPB + w * 2;
        #pragma unroll
        for (int r = 0; r < 2; ++r) {
            const int i = i0 + r;
            const float s1v = s1[i];
            const unsigned thr = (f2key(-s1v) & 0xFFFFE000u) | 0x1FFFu;
            // 3-round lane-parallel partition search: k = #{p: key[p] <= thr}
            const int pr1 = (sortedKey[lane * 128 + 127] <= thr) ? 1 : 0;
            const int B1 = __popcll(__ballot(pr1));
            int k;
            if (B1 >= 64) {
                k = NV;
            } else {
                const int base = B1 * 128;
                const int pr2 = (sortedKey[base + lane * 2 + 1] <= thr) ? 1 : 0;
                const int c2 = __popcll(__ballot(pr2));   // 0..63
                const int p3i = base + c2 * 2;
                k = p3i + ((sortedKey[p3i] <= thr) ? 1 : 0);
            }
            const int c = k >> 4;                 // CH=16; c in [0,512]
            float accU = 0.f, accV = 0.f, sau = 0.f, sav = 0.f;
            const int pst = c * CH;
            #pragma unroll
            for (int q = 0; q < CH; ++q) {
                const int p = pst + q;
                if (p < NV) {
                    const int j = sortedIdx[p];
                    const float wh = Wh[(size_t)j * FOUT + lane];
                    if (p < k) { const float v = sortedV[p]; accV = fmaf(v, wh, accV); sav += v; }
                    else       { const float u = sortedU[p]; accU = fmaf(u, wh, accU); sau += u; }
                }
            }
            const int cn = c + 1;
            const float A  = __expf(s1v);
            const float Bv = __expf(0.2f * s1v);
            const float numer = A * (Usuf[cn * FOUT + lane] + accU) + Bv * (Vpref[c * FOUT + lane] + accV);
            const float den   = A * (susuf[cn] + sau)               + Bv * (svpref[c] + sav);
            out[(size_t)i * FOUT + lane] = numer / den;
        }
    }
}

// ----------------------------------------------------------------
extern "C" void kernel_launch(void* const* d_in, const int* in_sizes, int n_in,
                              void* d_out, int out_size, void* d_ws, size_t ws_size,
                              hipStream_t stream) {
    (void)in_sizes; (void)n_in; (void)out_size; (void)ws_size;
    const float* h = (const float*)d_in[0];
    // d_in[1] = adj : unused by the reference computation
    const float* W = (const float*)d_in[2];
    const float* a = (const float*)d_in[3];
    float* out = (float*)d_out;

    unsigned* bar       = (unsigned*)d_ws;          // 16 slots (64 B)
    int*      sortedIdx = (int*)d_ws + 16;
    unsigned* sortedKey = (unsigned*)d_ws + 16 + NV;
    float* fws = (float*)d_ws + 16 + 2 * NV;
    float* Wh      = fws;  fws += (size_t)NV * FOUT;
    float* s1      = fws;  fws += NV;
    float* s2g     = fws;  fws += NV;
    float* sortedU = fws;  fws += NV;
    float* sortedV = fws;  fws += NV;
    float* chunkU  = fws;  fws += NCH * FOUT;
    float* chunkV  = fws;  fws += NCH * FOUT;
    float* suc     = fws;  fws += NCH;
    float* svc     = fws;  fws += NCH;
    float* Usuf    = fws;  fws += 514 * FOUT;
    float* Vpref   = fws;  fws += 513 * FOUT;
    float* susuf   = fws;  fws += 514;
    float* svpref  = fws;  fws += 513;

    // zero the barrier counters (captured into the graph -> runs every replay)
    hipMemsetAsync(bar, 0, 64, stream);

    int coopMode = 1, lo = 0, hi = 4;
    void* args[] = {
        (void*)&h, (void*)&W, (void*)&a, (void*)&out,
        (void*)&Wh, (void*)&s1, (void*)&s2g,
        (void*)&sortedIdx, (void*)&sortedKey, (void*)&sortedU, (void*)&sortedV,
        (void*)&chunkU, (void*)&chunkV, (void*)&suc, (void*)&svc,
        (void*)&Usuf, (void*)&Vpref, (void*)&susuf, (void*)&svpref,
        (void*)&bar, (void*)&coopMode, (void*)&lo, (void*)&hi
    };
    hipError_t err = hipLaunchCooperativeKernel(
        (const void*)gat_fused, dim3(NB), dim3(NT), args, 0, stream);

    if (err != hipSuccess) {
        // fallback: one launch per phase, barriers never executed
        for (int p = 0; p < 5; ++p) {
            hipLaunchKernelGGL(gat_fused, dim3(NB), dim3(NT), 0, stream,
                               h, W, a, out, Wh, s1, s2g,
                               sortedIdx, sortedKey, sortedU, sortedV,
                               chunkU, chunkV, suc, svc,
                               Usuf, Vpref, susuf, svpref,
                               bar, 0, p, p);
        }
    }
}

// Round 5
// 77.423 us; speedup vs baseline: 3.6414x; 2.5809x over previous
//
#include <hip/hip_runtime.h>

// GAT layer, N=8192, IN_F=512, OUT_F=64, alpha=0.2
// exp(lrelu(s1_i+s2_j)) factors on each side of s2_j <= -s1_i =>
// row_i = [A_i*suffixsum(exp(s2)*Wh) + B_i*prefixsum(exp(.2 s2)*Wh)] / (scalars)
// over s2 sorted ascending. O(N*F).
// 3 plain kernels, NO grid barriers (grid-wide sync measured 35-60us each on
// this 8-XCD part). kc is parallelized over (feature-slice x row-group) so the
// chunk-sum scan is BLOCK-LOCAL in LDS - no cross-block scan dependency.

constexpr int NV  = 8192;
constexpr int FIN = 512;
constexpr int NT  = 512;      // threads/block
constexpr int CH  = 16;       // sorted positions per chunk
constexpr int RPB = 16;       // ids per block in kb

__device__ __forceinline__ unsigned f2key(float x) {
    unsigned b = __float_as_uint(x);
    return (b & 0x80000000u) ? ~b : (b | 0x80000000u);  // order-preserving
}

// ================= kA: Wh = h @ W^T ; s1 = Wh@a1 ; s2 = Wh@a2 ==============
__global__ __launch_bounds__(NT, 4) void ka_gemm(
    const float* __restrict__ h, const float* __restrict__ W,
    const float* __restrict__ a, float* __restrict__ Wh,
    float* __restrict__ s1, float* __restrict__ s2g)
{
    __shared__ float smem[8192];   // 32 KB W-chunk
    const int t = threadIdx.x, b = blockIdx.x;
    const int lane = t & 63, w = t >> 6;
    const int row0 = __builtin_amdgcn_readfirstlane(b * 16 + w * 2);
    float4 A0 = {0.f,0.f,0.f,0.f}, A1 = {0.f,0.f,0.f,0.f};
    const float4* Wf4 = reinterpret_cast<const float4*>(W);
    float4* S4 = reinterpret_cast<float4*>(smem);
    for (int pass = 0; pass < 4; ++pass) {
        // stage W[:, pass*128 .. +128) into LDS, rotation-swizzled
        #pragma unroll
        for (int it = 0; it < 4; ++it) {
            const int g = it * 512 + t;          // 0..2047
            const int f = g >> 5, kk4 = g & 31;
            S4[kk4 * 64 + ((f + kk4) & 63)] = Wf4[f * 128 + pass * 32 + kk4];
        }
        __syncthreads();
        const float* hb = h + (size_t)row0 * FIN + pass * 128;
        #pragma unroll 8
        for (int k4 = 0; k4 < 32; ++k4) {
            const float4 wv = S4[k4 * 64 + ((lane + k4) & 63)];
            const float4 h0 = *reinterpret_cast<const float4*>(hb + k4 * 4);
            const float4 h1 = *reinterpret_cast<const float4*>(hb + FIN + k4 * 4);
            A0.x = fmaf(h0.x, wv.x, A0.x); A0.y = fmaf(h0.y, wv.y, A0.y);
            A0.z = fmaf(h0.z, wv.z, A0.z); A0.w = fmaf(h0.w, wv.w, A0.w);
            A1.x = fmaf(h1.x, wv.x, A1.x); A1.y = fmaf(h1.y, wv.y, A1.y);
            A1.z = fmaf(h1.z, wv.z, A1.z); A1.w = fmaf(h1.w, wv.w, A1.w);
        }
        __syncthreads();
    }
    const float acc0 = (A0.x + A0.y) + (A0.z + A0.w);
    const float acc1 = (A1.x + A1.y) + (A1.z + A1.w);
    Wh[(size_t)row0 * 64 + lane] = acc0;
    Wh[(size_t)(row0 + 1) * 64 + lane] = acc1;
    const float a1 = a[lane], a2 = a[64 + lane];
    float r0s1 = acc0 * a1, r0s2 = acc0 * a2;
    float r1s1 = acc1 * a1, r1s2 = acc1 * a2;
    #pragma unroll
    for (int off = 32; off > 0; off >>= 1) {
        r0s1 += __shfl_xor(r0s1, off);
        r0s2 += __shfl_xor(r0s2, off);
        r1s1 += __shfl_xor(r1s1, off);
        r1s2 += __shfl_xor(r1s2, off);
    }
    if (lane == 0) {
        s1[row0] = r0s1;     s2g[row0] = r0s2;
        s1[row0 + 1] = r1s1; s2g[row0 + 1] = r1s2;
    }
}

// ================= kB: rank by unique key, scatter sorted arrays ===========
__global__ __launch_bounds__(NT, 4) void kb_rank(
    const float* __restrict__ s2g,
    int* __restrict__ sortedIdx, unsigned* __restrict__ sortedKey,
    float* __restrict__ sortedU, float* __restrict__ sortedV)
{
    __shared__ unsigned ks[NV];
    #pragma unroll
    for (int q = 0; q < NV / NT; ++q) {
        const int j = q * NT + threadIdx.x;
        ks[j] = (f2key(s2g[j]) & 0xFFFFE000u) | (unsigned)j;  // unique keys
    }
    __syncthreads();
    const int seg = threadIdx.x & 31;             // 32 threads per id
    const int id  = blockIdx.x * RPB + (threadIdx.x >> 5);
    const unsigned key = ks[id];
    int cnt = 0;
    const uint4* K4 = reinterpret_cast<const uint4*>(ks);
    #pragma unroll 4
    for (int kk = 0; kk < 64; ++kk) {
        const uint4 v = K4[kk * 32 + seg];        // contiguous across lanes
        cnt += (int)(v.x < key) + (int)(v.y < key)
             + (int)(v.z < key) + (int)(v.w < key);
    }
    cnt += __shfl_xor(cnt, 1);
    cnt += __shfl_xor(cnt, 2);
    cnt += __shfl_xor(cnt, 4);
    cnt += __shfl_xor(cnt, 8);
    cnt += __shfl_xor(cnt, 16);
    if (seg == 0) {
        sortedKey[cnt] = key;
        sortedIdx[cnt] = id;
        const float x = s2g[id];
        sortedU[cnt] = __expf(x);
        sortedV[cnt] = __expf(0.2f * x);
    }
}

// ================= kC: block = (feature-slice, row-group); local scans =====
// fid = b&7 -> features [fid*8, fid*8+8); rg = b>>3 -> rows [rg*128, rg*128+128)
__global__ __launch_bounds__(NT, 4) void kc_out(
    const float* __restrict__ Wh, const float* __restrict__ s1,
    const unsigned* __restrict__ sortedKey, const int* __restrict__ sortedIdx,
    const float* __restrict__ sortedU, const float* __restrict__ sortedV,
    float* __restrict__ out)
{
    __shared__ unsigned kss[NV];          // 32 KB staged keys (binary search)
    __shared__ float Us[514 * 8];         // [c][f] inclusive suffix of chunkU
    __shared__ float Vp[513 * 8];         // [c][f] exclusive prefix of chunkV
    __shared__ float sus[514];            // scalar U suffix
    __shared__ float svp[513];            // scalar V exclusive prefix
    __shared__ float segTU[512], segTV[512], segSU[64], segSV[64];

    const int t = threadIdx.x, b = blockIdx.x;
    const int fid = b & 7;
    const int rg  = b >> 3;
    const int lane = t & 63, w = t >> 6;

    // stage keys (coalesced)
    #pragma unroll
    for (int q = 0; q < NV / NT; ++q) kss[q * NT + t] = sortedKey[q * NT + t];

    // ---- chunk sums: thread t owns chunk t (16 positions) for 8 features
    {
        float au[8] = {0.f,0.f,0.f,0.f,0.f,0.f,0.f,0.f};
        float av[8] = {0.f,0.f,0.f,0.f,0.f,0.f,0.f,0.f};
        float su = 0.f, sv = 0.f;
        const int p0 = t * CH;
        for (int q = 0; q < CH; ++q) {
            const int p = p0 + q;
            const int j = sortedIdx[p];
            const float u = sortedU[p];
            const float v = sortedV[p];
            const float4 w0 = *reinterpret_cast<const float4*>(Wh + (size_t)j * 64 + fid * 8);
            const float4 w1 = *reinterpret_cast<const float4*>(Wh + (size_t)j * 64 + fid * 8 + 4);
            au[0]=fmaf(u,w0.x,au[0]); au[1]=fmaf(u,w0.y,au[1]);
            au[2]=fmaf(u,w0.z,au[2]); au[3]=fmaf(u,w0.w,au[3]);
            au[4]=fmaf(u,w1.x,au[4]); au[5]=fmaf(u,w1.y,au[5]);
            au[6]=fmaf(u,w1.z,au[6]); au[7]=fmaf(u,w1.w,au[7]);
            av[0]=fmaf(v,w0.x,av[0]); av[1]=fmaf(v,w0.y,av[1]);
            av[2]=fmaf(v,w0.z,av[2]); av[3]=fmaf(v,w0.w,av[3]);
            av[4]=fmaf(v,w1.x,av[4]); av[5]=fmaf(v,w1.y,av[5]);
            av[6]=fmaf(v,w1.z,av[6]); av[7]=fmaf(v,w1.w,av[7]);
            su += u; sv += v;
        }
        #pragma unroll
        for (int e = 0; e < 8; ++e) { Us[t * 8 + e] = au[e]; Vp[t * 8 + e] = av[e]; }
        sus[t] = su; svp[t] = sv;
    }
    __syncthreads();

    // ---- first-level scans (in place): thread -> (f, seg of 8 chunks)
    const int f = t & 7, seg = t >> 3;    // seg 0..63
    {
        float run = 0.f;
        for (int q = 7; q >= 0; --q) { const int c = seg * 8 + q; run += Us[c * 8 + f]; Us[c * 8 + f] = run; }
        segTU[seg * 8 + f] = run;
        float runv = 0.f;
        for (int q = 0; q < 8; ++q) { const int c = seg * 8 + q; const float tmp = Vp[c * 8 + f]; Vp[c * 8 + f] = runv; runv += tmp; }
        segTV[seg * 8 + f] = runv;
        if (t < 64) {
            float r = 0.f;
            for (int q = 7; q >= 0; --q) { const int c = t * 8 + q; r += sus[c]; sus[c] = r; }
            segSU[t] = r;
            float rv = 0.f;
            for (int q = 0; q < 8; ++q) { const int c = t * 8 + q; const float tmp = svp[c]; svp[c] = rv; rv += tmp; }
            segSV[t] = rv;
        }
    }
    __syncthreads();

    // ---- second-level offsets
    {
        float offU = 0.f, offV = 0.f;
        for (int s = seg + 1; s < 64; ++s) offU += segTU[s * 8 + f];
        for (int s = 0; s < seg; ++s)      offV += segTV[s * 8 + f];
        for (int q = 0; q < 8; ++q) {
            const int c = seg * 8 + q;
            Us[c * 8 + f] += offU;
            Vp[c * 8 + f] += offV;
        }
        if (seg == 63) Vp[512 * 8 + f] = offV + segTV[63 * 8 + f];   // total
        if (t < 16) Us[512 * 8 + t] = 0.f;                           // c=512,513 pads
        if (t < 64) {
            float oU = 0.f, oV = 0.f;
            for (int s = t + 1; s < 64; ++s) oU += segSU[s];
            for (int s = 0; s < t; ++s)      oV += segSV[s];
            for (int q = 0; q < 8; ++q) { sus[t * 8 + q] += oU; svp[t * 8 + q] += oV; }
            if (t == 63) svp[512] = oV + segSV[63];
            if (t == 0) { sus[512] = 0.f; sus[513] = 0.f; }
        }
    }
    __syncthreads();

    // ---- outputs: wave w -> 16 rows; lane -> (row-slot g, feature fo)
    const int g = lane >> 3, fo = lane & 7;
    #pragma unroll
    for (int it = 0; it < 2; ++it) {
        const int i = rg * 128 + w * 16 + it * 8 + g;
        const float s1v = s1[i];
        const unsigned thr = (f2key(-s1v) & 0xFFFFE000u) | 0x1FFFu;
        int k = 0;                         // #{p: kss[p] <= thr}
        #pragma unroll
        for (int s = NV; s > 0; s >>= 1) {
            const int nk = k + s;
            if (nk <= NV && kss[nk - 1] <= thr) k = nk;
        }
        const int c = k >> 4;              // chunk of the cut, 0..512
        float accU = 0.f, accV = 0.f, sau = 0.f, sav = 0.f;
        const int pst = c * CH;
        #pragma unroll
        for (int q = 0; q < CH; ++q) {
            const int p = pst + q;
            if (p < NV) {
                const int j = sortedIdx[p];
                const float wv = Wh[(size_t)j * 64 + fid * 8 + fo];
                if (p < k) { const float v = sortedV[p]; accV = fmaf(v, wv, accV); sav += v; }
                else       { const float u = sortedU[p]; accU = fmaf(u, wv, accU); sau += u; }
            }
        }
        const float A = __expf(s1v), B = __expf(0.2f * s1v);
        const float numer = A * (Us[(c + 1) * 8 + fo] + accU) + B * (Vp[c * 8 + fo] + accV);
        const float den   = A * (sus[c + 1] + sau)            + B * (svp[c] + sav);
        out[(size_t)i * 64 + fid * 8 + fo] = numer / den;
    }
}

// ----------------------------------------------------------------
extern "C" void kernel_launch(void* const* d_in, const int* in_sizes, int n_in,
                              void* d_out, int out_size, void* d_ws, size_t ws_size,
                              hipStream_t stream) {
    (void)in_sizes; (void)n_in; (void)out_size; (void)ws_size;
    const float* h = (const float*)d_in[0];
    // d_in[1] = adj : unused by the reference computation
    const float* W = (const float*)d_in[2];
    const float* a = (const float*)d_in[3];
    float* out = (float*)d_out;

    int*      sortedIdx = (int*)d_ws;
    unsigned* sortedKey = (unsigned*)d_ws + NV;
    float* fws = (float*)d_ws + 2 * NV;
    float* Wh      = fws;  fws += (size_t)NV * 64;
    float* s1      = fws;  fws += NV;
    float* s2g     = fws;  fws += NV;
    float* sortedU = fws;  fws += NV;
    float* sortedV = fws;  fws += NV;

    hipLaunchKernelGGL(ka_gemm, dim3(512), dim3(NT), 0, stream, h, W, a, Wh, s1, s2g);
    hipLaunchKernelGGL(kb_rank, dim3(512), dim3(NT), 0, stream,
                       s2g, sortedIdx, sortedKey, sortedU, sortedV);
    hipLaunchKernelGGL(kc_out,  dim3(512), dim3(NT), 0, stream,
                       Wh, s1, sortedKey, sortedIdx, sortedU, sortedV, out);
}